// Round 2
// baseline (804.233 us; speedup 1.0000x reference)
//
#include <hip/hip_runtime.h>
#include <hip/hip_bf16.h>
#include <math.h>

#define NCELL 512          // 8^3 cells
#define IMG_F 16384        // NCELL * 32 floats = 64 KB

// ---------------------------------------------------------------------------
// K1: scatter points into per-block LDS lattices, write 64KB partial per block
// Plain atomicAdd on __shared__ float -> ds_add_f32 (HW LDS fp atomic,
// fire-and-forget; no lgkmcnt wait until the barrier). 1024 thr = 16 waves/CU.
// ---------------------------------------------------------------------------
__global__ __launch_bounds__(1024) void k_scatter(
    const float* __restrict__ pos,
    const float* __restrict__ feat,
    float* __restrict__ partials,
    int n)
{
    __shared__ float lat[IMG_F];   // 64 KB
    const int t = threadIdx.x;
    for (int i = t; i < IMG_F; i += 1024) lat[i] = 0.f;
    __syncthreads();

    const int c   = t & 31;        // channel lane
    const int sub = t >> 5;        // 0..31 point sub-slot
    const int chunk = (n + (int)gridDim.x - 1) / (int)gridDim.x;
    const int start = blockIdx.x * chunk;
    const int end   = min(start + chunk, n);

    #pragma unroll 2
    for (int p = start + sub; p < end; p += 32) {
        const float px = pos[3*p+0], py = pos[3*p+1], pz = pos[3*p+2];
        const float v  = feat[(size_t)p*32 + c];
        const float sx = px*8.f, sy = py*8.f, sz = pz*8.f;
        const float bx = floorf(sx), by = floorf(sy), bz = floorf(sz);
        const float fx = sx-bx, fy = sy-by, fz = sz-bz;
        const int ix = ((int)bx) & 7, iy = ((int)by) & 7, iz = ((int)bz) & 7;
        const int ix1 = (ix+1)&7, iy1 = (iy+1)&7, iz1 = (iz+1)&7;
        const float gx = 1.f-fx, gy = 1.f-fy, gz = 1.f-fz;
        // float addrs: cell*32 + c ; strides: x:2048, y:256, z:32
        const int x0 = ix*2048,  x1 = ix1*2048;
        const int y0 = iy*256,   y1 = iy1*256;
        const int z0 = iz*32+c,  z1 = iz1*32+c;
        const float w00 = gx*gy*v, w01 = gx*fy*v, w10 = fx*gy*v, w11 = fx*fy*v;
        // bank = c for every lane-group -> 2-way aliasing only (free)
        atomicAdd(&lat[x0+y0+z0], w00*gz);
        atomicAdd(&lat[x0+y0+z1], w00*fz);
        atomicAdd(&lat[x0+y1+z0], w01*gz);
        atomicAdd(&lat[x0+y1+z1], w01*fz);
        atomicAdd(&lat[x1+y0+z0], w10*gz);
        atomicAdd(&lat[x1+y0+z1], w10*fz);
        atomicAdd(&lat[x1+y1+z0], w11*gz);
        atomicAdd(&lat[x1+y1+z1], w11*fz);
    }
    __syncthreads();
    float4* __restrict__ dst = (float4*)(partials + (size_t)blockIdx.x * IMG_F);
    const float4* __restrict__ src = (const float4*)lat;
    for (int i = t; i < IMG_F/4; i += 1024) dst[i] = src[i];
}

// ---------------------------------------------------------------------------
// K2: reduce 256 partials -> img.  128 blocks x 256 thr, no atomics.
// ---------------------------------------------------------------------------
__global__ __launch_bounds__(256) void k_reduce(
    const float* __restrict__ partials,
    float* __restrict__ img)
{
    __shared__ float4 red[8][32];
    const int t = threadIdx.x;
    const int col = t & 31;
    const int g   = t >> 5;                      // 0..7: each group sums 32 rows
    const int col4 = blockIdx.x * 32 + col;      // 0..4095 (float4 columns)
    const float4* src = (const float4*)partials;
    float4 s = {0.f,0.f,0.f,0.f};
    for (int j = 0; j < 32; j++) {
        float4 v = src[(size_t)(g*32 + j) * (IMG_F/4) + col4];
        s.x += v.x; s.y += v.y; s.z += v.z; s.w += v.w;
    }
    red[g][col] = s;
    __syncthreads();
    if (g == 0) {
        float4 tot = red[0][col];
        #pragma unroll
        for (int gg = 1; gg < 8; gg++) {
            float4 v = red[gg][col];
            tot.x += v.x; tot.y += v.y; tot.z += v.z; tot.w += v.w;
        }
        ((float4*)img)[col4] = tot;
    }
}

// ---------------------------------------------------------------------------
// K3/K4/K5: periodic 3x3x3 conv, DHWOI weights [3][3][3][32][32].
// ACT=0: out = conv(in).  ACT=1: out = in + silu(conv(in)).
// Block = 256 thr handles 8 cells (one (ix,iy) column) x 32 couts.
// LDS: lattice staged as lds[cell*36 + cin]  (stride-36 pad: conflict-free,
// 16B aligned). Grid = 64 blocks.
// ---------------------------------------------------------------------------
template<int ACT>
__global__ __launch_bounds__(256) void k_conv(
    const float* __restrict__ in_lat,
    const float* __restrict__ w,
    float* __restrict__ out_lat)
{
    __shared__ float lds[NCELL*36];   // 73728 B
    const int t = threadIdx.x;
    for (int i = t; i < IMG_F/4; i += 256) {
        float4 v = ((const float4*)in_lat)[i];
        const int cell = i >> 3, c4 = i & 7;
        *(float4*)&lds[cell*36 + c4*4] = v;
    }
    __syncthreads();

    const int cout = t >> 3;                 // 0..31
    const int iz   = t & 7;                  // 0..7
    const int ix   = blockIdx.x >> 3, iy = blockIdx.x & 7;

    float4 acc = {0.f,0.f,0.f,0.f};
    #pragma unroll
    for (int kd = 0; kd < 3; kd++) {
      const int nx = (ix + kd + 7) & 7;
      #pragma unroll
      for (int kh = 0; kh < 3; kh++) {
        const int ny = (iy + kh + 7) & 7;
        #pragma unroll
        for (int kw = 0; kw < 3; kw++) {
          const int nz = (iz + kw + 7) & 7;
          const float* lrow = &lds[(nx*64 + ny*8 + nz)*36];
          const float* wrow = &w[(((kd*3 + kh)*3 + kw)*32 + cout)*32];
          #pragma unroll
          for (int c4i = 0; c4i < 8; c4i++) {
            const float4 a = *(const float4*)(lrow + c4i*4);
            const float4 b = *(const float4*)(wrow + c4i*4);
            acc.x = fmaf(a.x, b.x, acc.x);
            acc.y = fmaf(a.y, b.y, acc.y);
            acc.z = fmaf(a.z, b.z, acc.z);
            acc.w = fmaf(a.w, b.w, acc.w);
          }
        }
      }
    }
    float s = (acc.x + acc.y) + (acc.z + acc.w);
    const int oidx = (ix*64 + iy*8 + iz)*32 + cout;
    if (ACT == 1) {
        const float r = in_lat[oidx];
        s = r + s / (1.f + expf(-s));    // r + silu(conv)
    }
    out_lat[oidx] = s;
}

// ---------------------------------------------------------------------------
// K6: agg[cell] = sum over 8 corner-offset cells of out_lat  (512x32)
// ---------------------------------------------------------------------------
__global__ __launch_bounds__(256) void k_agg(
    const float* __restrict__ out_lat, float* __restrict__ agg)
{
    const int tid = blockIdx.x*256 + threadIdx.x;   // 0..4095
    if (tid >= 4096) return;
    const int cell = tid >> 3, c4 = tid & 7;
    const int ix = cell >> 6, iy = (cell >> 3) & 7, iz = cell & 7;
    float4 s = {0.f,0.f,0.f,0.f};
    #pragma unroll
    for (int k = 0; k < 8; k++) {
        const int nx = (ix + ((k>>2)&1)) & 7;
        const int ny = (iy + ((k>>1)&1)) & 7;
        const int nz = (iz + (k&1)) & 7;
        const float4 v = ((const float4*)out_lat)[(nx*64 + ny*8 + nz)*8 + c4];
        s.x += v.x; s.y += v.y; s.z += v.z; s.w += v.w;
    }
    ((float4*)agg)[tid] = s;
}

// ---------------------------------------------------------------------------
// K7: gather — out[p] = agg[base_cell(p)]  (pure table lookup, coalesced)
// ---------------------------------------------------------------------------
__global__ __launch_bounds__(256) void k_gather(
    const float* __restrict__ pos,
    const float* __restrict__ agg,
    float* __restrict__ out,
    int n)
{
    const int tid = blockIdx.x*256 + threadIdx.x;   // over n*8
    const int p = tid >> 3, c4 = tid & 7;
    if (p >= n) return;
    const int ix = ((int)floorf(pos[3*p+0]*8.f)) & 7;
    const int iy = ((int)floorf(pos[3*p+1]*8.f)) & 7;
    const int iz = ((int)floorf(pos[3*p+2]*8.f)) & 7;
    ((float4*)out)[tid] = ((const float4*)agg)[(ix*64 + iy*8 + iz)*8 + c4];
}

// ---------------------------------------------------------------------------
extern "C" void kernel_launch(void* const* d_in, const int* in_sizes, int n_in,
                              void* d_out, int out_size, void* d_ws, size_t ws_size,
                              hipStream_t stream)
{
    const float* pos  = (const float*)d_in[0];   // [N,3]
    const float* feat = (const float*)d_in[1];   // [N,32]
    const float* wenc = (const float*)d_in[2];   // [3,3,3,32,32]
    const float* winn = (const float*)d_in[3];   // [1,3,3,3,32,32]
    const float* wdec = (const float*)d_in[4];   // [3,3,3,32,32]
    float* out = (float*)d_out;
    const int n = in_sizes[0] / 3;

    float* ws       = (float*)d_ws;
    float* partials = ws;                         // 256 * 16384 floats (16 MB)
    float* img      = partials + 256*(size_t)IMG_F;
    float* h1       = img  + IMG_F;
    float* h2       = h1   + IMG_F;
    float* olat     = h2   + IMG_F;
    float* aggb     = olat + IMG_F;

    k_scatter<<<256, 1024, 0, stream>>>(pos, feat, partials, n);
    k_reduce <<<128, 256, 0, stream>>>(partials, img);
    k_conv<0><<<64, 256, 0, stream>>>(img, wenc, h1);
    k_conv<1><<<64, 256, 0, stream>>>(h1,  winn, h2);
    k_conv<0><<<64, 256, 0, stream>>>(h2,  wdec, olat);
    k_agg    <<<16, 256, 0, stream>>>(olat, aggb);
    const int gblocks = (n*8 + 255)/256;
    k_gather <<<gblocks, 256, 0, stream>>>(pos, aggb, out, n);
}

// Round 3
// 391.182 us; speedup vs baseline: 2.0559x; 2.0559x over previous
//
#include <hip/hip_runtime.h>
#include <hip/hip_bf16.h>
#include <math.h>

#define NCELL 512          // 8^3 cells
#define IMG_F 16384        // NCELL * 32 floats = 64 KB

// ---------------------------------------------------------------------------
// K0: histogram of base cells (LDS int atomics -> global int atomics)
// ---------------------------------------------------------------------------
__global__ __launch_bounds__(256) void k_hist(
    const float* __restrict__ pos, int n, int* __restrict__ binCount)
{
    __shared__ int h[NCELL];
    const int t = threadIdx.x;
    for (int i = t; i < NCELL; i += 256) h[i] = 0;
    __syncthreads();
    const int stride = gridDim.x * 256;
    for (int p = blockIdx.x * 256 + t; p < n; p += stride) {
        const int ix = ((int)floorf(pos[3*p+0]*8.f)) & 7;
        const int iy = ((int)floorf(pos[3*p+1]*8.f)) & 7;
        const int iz = ((int)floorf(pos[3*p+2]*8.f)) & 7;
        atomicAdd(&h[ix*64 + iy*8 + iz], 1);
    }
    __syncthreads();
    for (int i = t; i < NCELL; i += 256)
        if (h[i]) atomicAdd(&binCount[i], h[i]);
}

// ---------------------------------------------------------------------------
// K0b: exclusive prefix-sum of 512 bins -> binStart[513], cursor[512]
// ---------------------------------------------------------------------------
__global__ __launch_bounds__(512) void k_scan(
    const int* __restrict__ cnt, int* __restrict__ binStart, int* __restrict__ cursor)
{
    __shared__ int s[NCELL];
    const int t = threadIdx.x;
    const int v = cnt[t];
    s[t] = v;
    __syncthreads();
    int acc = v;
    for (int off = 1; off < NCELL; off <<= 1) {
        const int add = (t >= off) ? s[t - off] : 0;
        __syncthreads();
        acc += add;
        s[t] = acc;
        __syncthreads();
    }
    binStart[t] = acc - v;     // exclusive
    cursor[t]   = acc - v;
    if (t == NCELL - 1) binStart[NCELL] = acc;
}

// ---------------------------------------------------------------------------
// K0c: reorder -- write per-point meta {fx,fy,fz,idx} into cell-sorted slots
// ---------------------------------------------------------------------------
__global__ __launch_bounds__(256) void k_reorder(
    const float* __restrict__ pos, int n,
    int* __restrict__ cursor, float4* __restrict__ meta)
{
    const int stride = gridDim.x * 256;
    for (int p = blockIdx.x * 256 + threadIdx.x; p < n; p += stride) {
        const float sx = pos[3*p+0]*8.f, sy = pos[3*p+1]*8.f, sz = pos[3*p+2]*8.f;
        const float bx = floorf(sx), by = floorf(sy), bz = floorf(sz);
        const int ix = ((int)bx) & 7, iy = ((int)by) & 7, iz = ((int)bz) & 7;
        const int cell = ix*64 + iy*8 + iz;
        const int slot = atomicAdd(&cursor[cell], 1);
        meta[slot] = make_float4(sx - bx, sy - by, sz - bz, __int_as_float(p));
    }
}

// ---------------------------------------------------------------------------
// K1: per-cell register accumulation of M[8][32] = sum_p w[8] (x) feat[32].
// Block = cell. 256 thr: c = t&31 (channel), sub = t>>5 (8 point subsets).
// Zero fp atomics; feat rows are coalesced 128B reads.
// ---------------------------------------------------------------------------
__global__ __launch_bounds__(256) void k_accum(
    const float4* __restrict__ meta,
    const float* __restrict__ feat,
    const int* __restrict__ binStart,
    float* __restrict__ Mbuf)
{
    const int cell = blockIdx.x;
    const int t = threadIdx.x;
    const int c = t & 31, sub = t >> 5;
    const int i0 = binStart[cell], i1 = binStart[cell + 1];

    float acc[8];
    #pragma unroll
    for (int k = 0; k < 8; k++) acc[k] = 0.f;

    #pragma unroll 2
    for (int i = i0 + sub; i < i1; i += 8) {
        const float4 m = meta[i];
        const int idx = __float_as_int(m.w);
        const float v = feat[(size_t)idx * 32 + c];
        const float gx = 1.f - m.x, gy = 1.f - m.y, gz = 1.f - m.z;
        const float a00 = gx * gy, a01 = gx * m.y, a10 = m.x * gy, a11 = m.x * m.y;
        acc[0] = fmaf(a00 * gz,  v, acc[0]);
        acc[1] = fmaf(a00 * m.z, v, acc[1]);
        acc[2] = fmaf(a01 * gz,  v, acc[2]);
        acc[3] = fmaf(a01 * m.z, v, acc[3]);
        acc[4] = fmaf(a10 * gz,  v, acc[4]);
        acc[5] = fmaf(a10 * m.z, v, acc[5]);
        acc[6] = fmaf(a11 * gz,  v, acc[6]);
        acc[7] = fmaf(a11 * m.z, v, acc[7]);
    }

    // reduce 8 subsets: red[sub][k][c]
    __shared__ float red[8 * 8 * 32];
    #pragma unroll
    for (int k = 0; k < 8; k++) red[sub*256 + k*32 + c] = acc[k];
    __syncthreads();
    // thread t -> output (k = t>>5, c = t&31)
    const int k = sub;
    float s = 0.f;
    #pragma unroll
    for (int ss = 0; ss < 8; ss++) s += red[ss*256 + k*32 + c];
    Mbuf[(cell*8 + k)*32 + c] = s;
}

// ---------------------------------------------------------------------------
// K2: deterministic flush: img[x,y,z][c] = sum_{dx,dy,dz} M[(x-dx)&7,...][k][c]
// ---------------------------------------------------------------------------
__global__ __launch_bounds__(256) void k_flush(
    const float* __restrict__ Mbuf, float* __restrict__ img)
{
    const int tid = blockIdx.x*256 + threadIdx.x;   // 0..4095 (float4 units)
    if (tid >= 4096) return;
    const int cell = tid >> 3, c4 = tid & 7;
    const int x = cell >> 6, y = (cell >> 3) & 7, z = cell & 7;
    const float4* M4 = (const float4*)Mbuf;         // [512][8][8]
    float4 s = {0.f, 0.f, 0.f, 0.f};
    #pragma unroll
    for (int k = 0; k < 8; k++) {
        const int dx = (k >> 2) & 1, dy = (k >> 1) & 1, dz = k & 1;
        const int b = ((x - dx) & 7)*64 + ((y - dy) & 7)*8 + ((z - dz) & 7);
        const float4 v = M4[(b*8 + k)*8 + c4];
        s.x += v.x; s.y += v.y; s.z += v.z; s.w += v.w;
    }
    ((float4*)img)[tid] = s;
}

// ---------------------------------------------------------------------------
// K3/K4/K5: periodic 3x3x3 conv, DHWOI weights [3][3][3][32][32].
// ACT=0: out = conv(in).  ACT=1: out = in + silu(conv(in)).
// ---------------------------------------------------------------------------
template<int ACT>
__global__ __launch_bounds__(256) void k_conv(
    const float* __restrict__ in_lat,
    const float* __restrict__ w,
    float* __restrict__ out_lat)
{
    __shared__ float lds[NCELL*36];   // stride-36 pad, conflict-free
    const int t = threadIdx.x;
    for (int i = t; i < IMG_F/4; i += 256) {
        float4 v = ((const float4*)in_lat)[i];
        const int cell = i >> 3, c4 = i & 7;
        *(float4*)&lds[cell*36 + c4*4] = v;
    }
    __syncthreads();

    const int cout = t >> 3;                 // 0..31
    const int iz   = t & 7;                  // 0..7
    const int ix   = blockIdx.x >> 3, iy = blockIdx.x & 7;

    float4 acc = {0.f,0.f,0.f,0.f};
    #pragma unroll
    for (int kd = 0; kd < 3; kd++) {
      const int nx = (ix + kd + 7) & 7;
      #pragma unroll
      for (int kh = 0; kh < 3; kh++) {
        const int ny = (iy + kh + 7) & 7;
        #pragma unroll
        for (int kw = 0; kw < 3; kw++) {
          const int nz = (iz + kw + 7) & 7;
          const float* lrow = &lds[(nx*64 + ny*8 + nz)*36];
          const float* wrow = &w[(((kd*3 + kh)*3 + kw)*32 + cout)*32];
          #pragma unroll
          for (int c4i = 0; c4i < 8; c4i++) {
            const float4 a = *(const float4*)(lrow + c4i*4);
            const float4 b = *(const float4*)(wrow + c4i*4);
            acc.x = fmaf(a.x, b.x, acc.x);
            acc.y = fmaf(a.y, b.y, acc.y);
            acc.z = fmaf(a.z, b.z, acc.z);
            acc.w = fmaf(a.w, b.w, acc.w);
          }
        }
      }
    }
    float s = (acc.x + acc.y) + (acc.z + acc.w);
    const int oidx = (ix*64 + iy*8 + iz)*32 + cout;
    if (ACT == 1) {
        const float r = in_lat[oidx];
        s = r + s / (1.f + expf(-s));    // r + silu(conv)
    }
    out_lat[oidx] = s;
}

// ---------------------------------------------------------------------------
// K6: agg[cell] = sum over 8 corner-offset cells of out_lat
// ---------------------------------------------------------------------------
__global__ __launch_bounds__(256) void k_agg(
    const float* __restrict__ out_lat, float* __restrict__ agg)
{
    const int tid = blockIdx.x*256 + threadIdx.x;   // 0..4095
    if (tid >= 4096) return;
    const int cell = tid >> 3, c4 = tid & 7;
    const int ix = cell >> 6, iy = (cell >> 3) & 7, iz = cell & 7;
    float4 s = {0.f,0.f,0.f,0.f};
    #pragma unroll
    for (int k = 0; k < 8; k++) {
        const int nx = (ix + ((k>>2)&1)) & 7;
        const int ny = (iy + ((k>>1)&1)) & 7;
        const int nz = (iz + (k&1)) & 7;
        const float4 v = ((const float4*)out_lat)[(nx*64 + ny*8 + nz)*8 + c4];
        s.x += v.x; s.y += v.y; s.z += v.z; s.w += v.w;
    }
    ((float4*)agg)[tid] = s;
}

// ---------------------------------------------------------------------------
// K7: gather -- out[p] = agg[base_cell(p)]
// ---------------------------------------------------------------------------
__global__ __launch_bounds__(256) void k_gather(
    const float* __restrict__ pos,
    const float* __restrict__ agg,
    float* __restrict__ out,
    int n)
{
    const int tid = blockIdx.x*256 + threadIdx.x;   // over n*8
    const int p = tid >> 3, c4 = tid & 7;
    if (p >= n) return;
    const int ix = ((int)floorf(pos[3*p+0]*8.f)) & 7;
    const int iy = ((int)floorf(pos[3*p+1]*8.f)) & 7;
    const int iz = ((int)floorf(pos[3*p+2]*8.f)) & 7;
    ((float4*)out)[tid] = ((const float4*)agg)[(ix*64 + iy*8 + iz)*8 + c4];
}

// ---------------------------------------------------------------------------
extern "C" void kernel_launch(void* const* d_in, const int* in_sizes, int n_in,
                              void* d_out, int out_size, void* d_ws, size_t ws_size,
                              hipStream_t stream)
{
    const float* pos  = (const float*)d_in[0];   // [N,3]
    const float* feat = (const float*)d_in[1];   // [N,32]
    const float* wenc = (const float*)d_in[2];   // [3,3,3,32,32]
    const float* winn = (const float*)d_in[3];   // [1,3,3,3,32,32]
    const float* wdec = (const float*)d_in[4];   // [3,3,3,32,32]
    float* out = (float*)d_out;
    const int n = in_sizes[0] / 3;

    // ws layout (16B-aligned blocks first)
    float4* meta   = (float4*)d_ws;                         // n float4  (8 MB)
    float*  Mbuf   = (float*)(meta + n);                    // 512*8*32 floats
    float*  img    = Mbuf + NCELL*8*32;
    float*  h1     = img  + IMG_F;
    float*  h2     = h1   + IMG_F;
    float*  olat   = h2   + IMG_F;
    float*  aggb   = olat + IMG_F;
    int*    binCount = (int*)(aggb + IMG_F);                // 512
    int*    binStart = binCount + NCELL;                    // 513
    int*    cursor   = binStart + NCELL + 1;                // 512

    hipMemsetAsync(binCount, 0, NCELL * sizeof(int), stream);
    k_hist   <<<128, 256, 0, stream>>>(pos, n, binCount);
    k_scan   <<<1,   512, 0, stream>>>(binCount, binStart, cursor);
    k_reorder<<<256, 256, 0, stream>>>(pos, n, cursor, meta);
    k_accum  <<<NCELL, 256, 0, stream>>>(meta, feat, binStart, Mbuf);
    k_flush  <<<16,  256, 0, stream>>>(Mbuf, img);
    k_conv<0><<<64,  256, 0, stream>>>(img, wenc, h1);
    k_conv<1><<<64,  256, 0, stream>>>(h1,  winn, h2);
    k_conv<0><<<64,  256, 0, stream>>>(h2,  wdec, olat);
    k_agg    <<<16,  256, 0, stream>>>(olat, aggb);
    const int gblocks = (n*8 + 255)/256;
    k_gather <<<gblocks, 256, 0, stream>>>(pos, aggb, out, n);
}

// Round 4
// 251.335 us; speedup vs baseline: 3.1998x; 1.5564x over previous
//
#include <hip/hip_runtime.h>
#include <hip/hip_bf16.h>
#include <math.h>

#define NCELL 512          // 8^3 cells
#define IMG_F 16384        // NCELL * 32 floats = 64 KB
#define NB    128          // sort blocks (hist/reorder must use same grid)

// ---------------------------------------------------------------------------
// K0: per-block histogram of base cells -> blockCnt[b][cell]  (no global atomics)
// ---------------------------------------------------------------------------
__global__ __launch_bounds__(256) void k_hist(
    const float* __restrict__ pos, int n, int* __restrict__ blockCnt)
{
    __shared__ int h[NCELL];
    const int t = threadIdx.x;
    for (int i = t; i < NCELL; i += 256) h[i] = 0;
    __syncthreads();
    const int stride = NB * 256;
    for (int p = blockIdx.x * 256 + t; p < n; p += stride) {
        const int ix = ((int)floorf(pos[3*p+0]*8.f)) & 7;
        const int iy = ((int)floorf(pos[3*p+1]*8.f)) & 7;
        const int iz = ((int)floorf(pos[3*p+2]*8.f)) & 7;
        atomicAdd(&h[ix*64 + iy*8 + iz], 1);
    }
    __syncthreads();
    for (int i = t; i < NCELL; i += 256)
        blockCnt[blockIdx.x * NCELL + i] = h[i];
}

// ---------------------------------------------------------------------------
// K0b: per-cell column scan over blocks + cell scan -> blockBase, binStart
// 1 block x 512 threads (thread = cell).
// ---------------------------------------------------------------------------
__global__ __launch_bounds__(512) void k_offsets(
    const int* __restrict__ blockCnt,
    int* __restrict__ blockBase,
    int* __restrict__ binStart)
{
    const int t = threadIdx.x;          // cell id
    int running = 0;
    for (int b = 0; b < NB; b++) {
        const int v = blockCnt[b * NCELL + t];
        blockBase[b * NCELL + t] = running;
        running += v;
    }
    // exclusive scan of per-cell totals across cells
    __shared__ int s[NCELL];
    s[t] = running;
    __syncthreads();
    int acc = running;
    for (int off = 1; off < NCELL; off <<= 1) {
        const int add = (t >= off) ? s[t - off] : 0;
        __syncthreads();
        acc += add;
        s[t] = acc;
        __syncthreads();
    }
    const int excl = acc - running;
    binStart[t] = excl;
    if (t == NCELL - 1) binStart[NCELL] = acc;
    for (int b = 0; b < NB; b++)
        blockBase[b * NCELL + t] += excl;
}

// ---------------------------------------------------------------------------
// K0c: reorder -- same point partition as k_hist; slots from LDS cursors
// seeded with blockBase[b][cell]. Zero global atomics.
// ---------------------------------------------------------------------------
__global__ __launch_bounds__(256) void k_reorder(
    const float* __restrict__ pos, int n,
    const int* __restrict__ blockBase, float4* __restrict__ meta)
{
    __shared__ int cur[NCELL];
    const int t = threadIdx.x;
    for (int i = t; i < NCELL; i += 256) cur[i] = blockBase[blockIdx.x * NCELL + i];
    __syncthreads();
    const int stride = NB * 256;
    for (int p = blockIdx.x * 256 + t; p < n; p += stride) {
        const float sx = pos[3*p+0]*8.f, sy = pos[3*p+1]*8.f, sz = pos[3*p+2]*8.f;
        const float bx = floorf(sx), by = floorf(sy), bz = floorf(sz);
        const int ix = ((int)bx) & 7, iy = ((int)by) & 7, iz = ((int)bz) & 7;
        const int cell = ix*64 + iy*8 + iz;
        const int slot = atomicAdd(&cur[cell], 1);     // LDS ds_add_rtn
        meta[slot] = make_float4(sx - bx, sy - by, sz - bz, __int_as_float(p));
    }
}

// ---------------------------------------------------------------------------
// K1: per-cell register accumulation of M[8][32] = sum_p w[8] (x) feat[32].
// Block = cell, 512 thr: c = t&31 (channel), sub = t>>5 (16 point subsets).
// ---------------------------------------------------------------------------
__global__ __launch_bounds__(512) void k_accum(
    const float4* __restrict__ meta,
    const float* __restrict__ feat,
    const int* __restrict__ binStart,
    float* __restrict__ Mbuf)
{
    const int cell = blockIdx.x;
    const int t = threadIdx.x;
    const int c = t & 31, sub = t >> 5;       // sub in 0..15
    const int i0 = binStart[cell], i1 = binStart[cell + 1];

    float acc[8];
    #pragma unroll
    for (int k = 0; k < 8; k++) acc[k] = 0.f;

    #pragma unroll 2
    for (int i = i0 + sub; i < i1; i += 16) {
        const float4 m = meta[i];
        const int idx = __float_as_int(m.w);
        const float v = feat[(size_t)idx * 32 + c];
        const float gx = 1.f - m.x, gy = 1.f - m.y, gz = 1.f - m.z;
        const float a00 = gx * gy, a01 = gx * m.y, a10 = m.x * gy, a11 = m.x * m.y;
        acc[0] = fmaf(a00 * gz,  v, acc[0]);
        acc[1] = fmaf(a00 * m.z, v, acc[1]);
        acc[2] = fmaf(a01 * gz,  v, acc[2]);
        acc[3] = fmaf(a01 * m.z, v, acc[3]);
        acc[4] = fmaf(a10 * gz,  v, acc[4]);
        acc[5] = fmaf(a10 * m.z, v, acc[5]);
        acc[6] = fmaf(a11 * gz,  v, acc[6]);
        acc[7] = fmaf(a11 * m.z, v, acc[7]);
    }

    // reduce 16 subsets: red[sub][k][c]
    __shared__ float red[16 * 8 * 32];
    #pragma unroll
    for (int k = 0; k < 8; k++) red[sub*256 + k*32 + c] = acc[k];
    __syncthreads();
    if (t < 256) {
        const int k = t >> 5, cc = t & 31;
        float s = 0.f;
        #pragma unroll
        for (int ss = 0; ss < 16; ss++) s += red[ss*256 + k*32 + cc];
        Mbuf[(cell*8 + k)*32 + cc] = s;
    }
}

// ---------------------------------------------------------------------------
// K2: deterministic flush: img[x,y,z][c] = sum_{dx,dy,dz} M[(x-dx)&7,...][k][c]
// ---------------------------------------------------------------------------
__global__ __launch_bounds__(256) void k_flush(
    const float* __restrict__ Mbuf, float* __restrict__ img)
{
    const int tid = blockIdx.x*256 + threadIdx.x;   // 0..4095 (float4 units)
    if (tid >= 4096) return;
    const int cell = tid >> 3, c4 = tid & 7;
    const int x = cell >> 6, y = (cell >> 3) & 7, z = cell & 7;
    const float4* M4 = (const float4*)Mbuf;         // [512][8][8]
    float4 s = {0.f, 0.f, 0.f, 0.f};
    #pragma unroll
    for (int k = 0; k < 8; k++) {
        const int dx = (k >> 2) & 1, dy = (k >> 1) & 1, dz = k & 1;
        const int b = ((x - dx) & 7)*64 + ((y - dy) & 7)*8 + ((z - dz) & 7);
        const float4 v = M4[(b*8 + k)*8 + c4];
        s.x += v.x; s.y += v.y; s.z += v.z; s.w += v.w;
    }
    ((float4*)img)[tid] = s;
}

// ---------------------------------------------------------------------------
// K3/K4/K5: periodic 3x3x3 conv, DHWOI weights [3][3][3][32][32].
// ACT=0: out = conv(in).  ACT=1: out = in + silu(conv(in)).
// ---------------------------------------------------------------------------
template<int ACT>
__global__ __launch_bounds__(256) void k_conv(
    const float* __restrict__ in_lat,
    const float* __restrict__ w,
    float* __restrict__ out_lat)
{
    __shared__ float lds[NCELL*36];   // stride-36 pad, conflict-free
    const int t = threadIdx.x;
    for (int i = t; i < IMG_F/4; i += 256) {
        float4 v = ((const float4*)in_lat)[i];
        const int cell = i >> 3, c4 = i & 7;
        *(float4*)&lds[cell*36 + c4*4] = v;
    }
    __syncthreads();

    const int cout = t >> 3;                 // 0..31
    const int iz   = t & 7;                  // 0..7
    const int ix   = blockIdx.x >> 3, iy = blockIdx.x & 7;

    float4 acc = {0.f,0.f,0.f,0.f};
    #pragma unroll
    for (int kd = 0; kd < 3; kd++) {
      const int nx = (ix + kd + 7) & 7;
      #pragma unroll
      for (int kh = 0; kh < 3; kh++) {
        const int ny = (iy + kh + 7) & 7;
        #pragma unroll
        for (int kw = 0; kw < 3; kw++) {
          const int nz = (iz + kw + 7) & 7;
          const float* lrow = &lds[(nx*64 + ny*8 + nz)*36];
          const float* wrow = &w[(((kd*3 + kh)*3 + kw)*32 + cout)*32];
          #pragma unroll
          for (int c4i = 0; c4i < 8; c4i++) {
            const float4 a = *(const float4*)(lrow + c4i*4);
            const float4 b = *(const float4*)(wrow + c4i*4);
            acc.x = fmaf(a.x, b.x, acc.x);
            acc.y = fmaf(a.y, b.y, acc.y);
            acc.z = fmaf(a.z, b.z, acc.z);
            acc.w = fmaf(a.w, b.w, acc.w);
          }
        }
      }
    }
    float s = (acc.x + acc.y) + (acc.z + acc.w);
    const int oidx = (ix*64 + iy*8 + iz)*32 + cout;
    if (ACT == 1) {
        const float r = in_lat[oidx];
        s = r + s / (1.f + expf(-s));    // r + silu(conv)
    }
    out_lat[oidx] = s;
}

// ---------------------------------------------------------------------------
// K6: agg[cell] = sum over 8 corner-offset cells of out_lat
// ---------------------------------------------------------------------------
__global__ __launch_bounds__(256) void k_agg(
    const float* __restrict__ out_lat, float* __restrict__ agg)
{
    const int tid = blockIdx.x*256 + threadIdx.x;   // 0..4095
    if (tid >= 4096) return;
    const int cell = tid >> 3, c4 = tid & 7;
    const int ix = cell >> 6, iy = (cell >> 3) & 7, iz = cell & 7;
    float4 s = {0.f,0.f,0.f,0.f};
    #pragma unroll
    for (int k = 0; k < 8; k++) {
        const int nx = (ix + ((k>>2)&1)) & 7;
        const int ny = (iy + ((k>>1)&1)) & 7;
        const int nz = (iz + (k&1)) & 7;
        const float4 v = ((const float4*)out_lat)[(nx*64 + ny*8 + nz)*8 + c4];
        s.x += v.x; s.y += v.y; s.z += v.z; s.w += v.w;
    }
    ((float4*)agg)[tid] = s;
}

// ---------------------------------------------------------------------------
// K7: gather -- out[p] = agg[base_cell(p)]
// ---------------------------------------------------------------------------
__global__ __launch_bounds__(256) void k_gather(
    const float* __restrict__ pos,
    const float* __restrict__ agg,
    float* __restrict__ out,
    int n)
{
    const int tid = blockIdx.x*256 + threadIdx.x;   // over n*8
    const int p = tid >> 3, c4 = tid & 7;
    if (p >= n) return;
    const int ix = ((int)floorf(pos[3*p+0]*8.f)) & 7;
    const int iy = ((int)floorf(pos[3*p+1]*8.f)) & 7;
    const int iz = ((int)floorf(pos[3*p+2]*8.f)) & 7;
    ((float4*)out)[tid] = ((const float4*)agg)[(ix*64 + iy*8 + iz)*8 + c4];
}

// ---------------------------------------------------------------------------
extern "C" void kernel_launch(void* const* d_in, const int* in_sizes, int n_in,
                              void* d_out, int out_size, void* d_ws, size_t ws_size,
                              hipStream_t stream)
{
    const float* pos  = (const float*)d_in[0];   // [N,3]
    const float* feat = (const float*)d_in[1];   // [N,32]
    const float* wenc = (const float*)d_in[2];   // [3,3,3,32,32]
    const float* winn = (const float*)d_in[3];   // [1,3,3,3,32,32]
    const float* wdec = (const float*)d_in[4];   // [3,3,3,32,32]
    float* out = (float*)d_out;
    const int n = in_sizes[0] / 3;

    // ws layout (16B-aligned blocks first)
    float4* meta     = (float4*)d_ws;                       // n float4 (8 MB)
    float*  Mbuf     = (float*)(meta + n);                  // 512*8*32 floats
    float*  img      = Mbuf + NCELL*8*32;
    float*  h1       = img  + IMG_F;
    float*  h2       = h1   + IMG_F;
    float*  olat     = h2   + IMG_F;
    float*  aggb     = olat + IMG_F;
    int*    blockCnt = (int*)(aggb + IMG_F);                // NB*512
    int*    blockBase= blockCnt + NB*NCELL;                 // NB*512
    int*    binStart = blockBase + NB*NCELL;                // 513

    k_hist   <<<NB,  256, 0, stream>>>(pos, n, blockCnt);
    k_offsets<<<1,   512, 0, stream>>>(blockCnt, blockBase, binStart);
    k_reorder<<<NB,  256, 0, stream>>>(pos, n, blockBase, meta);
    k_accum  <<<NCELL, 512, 0, stream>>>(meta, feat, binStart, Mbuf);
    k_flush  <<<16,  256, 0, stream>>>(Mbuf, img);
    k_conv<0><<<64,  256, 0, stream>>>(img, wenc, h1);
    k_conv<1><<<64,  256, 0, stream>>>(h1,  winn, h2);
    k_conv<0><<<64,  256, 0, stream>>>(h2,  wdec, olat);
    k_agg    <<<16,  256, 0, stream>>>(olat, aggb);
    const int gblocks = (n*8 + 255)/256;
    k_gather <<<gblocks, 256, 0, stream>>>(pos, aggb, out, n);
}

// Round 5
// 199.306 us; speedup vs baseline: 4.0352x; 1.2611x over previous
//
#include <hip/hip_runtime.h>
#include <hip/hip_bf16.h>
#include <math.h>

#define NCELL 512          // 8^3 cells
#define IMG_F 16384        // NCELL * 32 floats = 64 KB
#define NB    256          // sort blocks (hist/reorder share this grid)
#define SPLIT 4            // accum blocks per cell

// ---------------------------------------------------------------------------
// K0: per-block histogram -> blockCnt[cell][b]   (no global atomics)
// ---------------------------------------------------------------------------
__global__ __launch_bounds__(256) void k_hist(
    const float* __restrict__ pos, int n, int* __restrict__ blockCnt)
{
    __shared__ int h[NCELL];
    const int t = threadIdx.x;
    for (int i = t; i < NCELL; i += 256) h[i] = 0;
    __syncthreads();
    const int stride = NB * 256;
    for (int p = blockIdx.x * 256 + t; p < n; p += stride) {
        const int ix = ((int)floorf(pos[3*p+0]*8.f)) & 7;
        const int iy = ((int)floorf(pos[3*p+1]*8.f)) & 7;
        const int iz = ((int)floorf(pos[3*p+2]*8.f)) & 7;
        atomicAdd(&h[ix*64 + iy*8 + iz], 1);
    }
    __syncthreads();
    for (int i = t; i < NCELL; i += 256)
        blockCnt[i * NB + blockIdx.x] = h[i];
}

// ---------------------------------------------------------------------------
// K0b: per-cell scan over the NB blocks. block = cell, thread = sort-block.
// relBase[cell][b] = exclusive prefix; cellTot[cell] = total.
// ---------------------------------------------------------------------------
__global__ __launch_bounds__(NB) void k_colscan(
    const int* __restrict__ blockCnt,
    int* __restrict__ relBase,
    int* __restrict__ cellTot)
{
    __shared__ int s[NB];
    const int cell = blockIdx.x, b = threadIdx.x;
    const int v = blockCnt[cell * NB + b];     // coalesced
    s[b] = v;
    __syncthreads();
    int acc = v;
    for (int off = 1; off < NB; off <<= 1) {
        const int add = (b >= off) ? s[b - off] : 0;
        __syncthreads();
        acc += add;
        s[b] = acc;
        __syncthreads();
    }
    relBase[cell * NB + b] = acc - v;
    if (b == NB - 1) cellTot[cell] = acc;
}

// ---------------------------------------------------------------------------
// K0c: exclusive scan of 512 cell totals -> binStart[513]
// ---------------------------------------------------------------------------
__global__ __launch_bounds__(NCELL) void k_scan512(
    const int* __restrict__ cellTot, int* __restrict__ binStart)
{
    __shared__ int s[NCELL];
    const int t = threadIdx.x;
    const int v = cellTot[t];
    s[t] = v;
    __syncthreads();
    int acc = v;
    for (int off = 1; off < NCELL; off <<= 1) {
        const int add = (t >= off) ? s[t - off] : 0;
        __syncthreads();
        acc += add;
        s[t] = acc;
        __syncthreads();
    }
    binStart[t] = acc - v;
    if (t == NCELL - 1) binStart[NCELL] = acc;
}

// ---------------------------------------------------------------------------
// K0d: reorder -- same point partition as k_hist; slots from LDS cursors
// seeded with binStart[cell] + relBase[cell][b]. Zero global atomics.
// ---------------------------------------------------------------------------
__global__ __launch_bounds__(256) void k_reorder(
    const float* __restrict__ pos, int n,
    const int* __restrict__ relBase, const int* __restrict__ binStart,
    float4* __restrict__ meta)
{
    __shared__ int cur[NCELL];
    const int t = threadIdx.x;
    for (int i = t; i < NCELL; i += 256)
        cur[i] = binStart[i] + relBase[i * NB + blockIdx.x];
    __syncthreads();
    const int stride = NB * 256;
    for (int p = blockIdx.x * 256 + t; p < n; p += stride) {
        const float sx = pos[3*p+0]*8.f, sy = pos[3*p+1]*8.f, sz = pos[3*p+2]*8.f;
        const float bx = floorf(sx), by = floorf(sy), bz = floorf(sz);
        const int ix = ((int)bx) & 7, iy = ((int)by) & 7, iz = ((int)bz) & 7;
        const int cell = ix*64 + iy*8 + iz;
        const int slot = atomicAdd(&cur[cell], 1);     // LDS ds_add_rtn
        meta[slot] = make_float4(sx - bx, sy - by, sz - bz, __int_as_float(p));
    }
}

// ---------------------------------------------------------------------------
// K1: per-(cell,split) register accumulation of M[8][32].
// grid = NCELL*SPLIT, 512 thr: c = t&31, sub = t>>5 (16 point subsets).
// 4 blocks/CU (16KB LDS, 24 VGPR) -> ~100% occupancy for latency hiding.
// ---------------------------------------------------------------------------
__global__ __launch_bounds__(512) void k_accum(
    const float4* __restrict__ meta,
    const float* __restrict__ feat,
    const int* __restrict__ binStart,
    float* __restrict__ Mbuf)
{
    const int cell  = blockIdx.x >> 2;
    const int split = blockIdx.x & (SPLIT - 1);
    const int t = threadIdx.x;
    const int c = t & 31, sub = t >> 5;       // sub in 0..15
    const int b0 = binStart[cell], cnt = binStart[cell + 1] - b0;
    const int s0 = b0 + (cnt * split) / SPLIT;
    const int s1 = b0 + (cnt * (split + 1)) / SPLIT;

    float acc[8];
    #pragma unroll
    for (int k = 0; k < 8; k++) acc[k] = 0.f;

    #pragma unroll 2
    for (int i = s0 + sub; i < s1; i += 16) {
        const float4 m = meta[i];
        const int idx = __float_as_int(m.w);
        const float v = feat[(size_t)idx * 32 + c];
        const float gx = 1.f - m.x, gy = 1.f - m.y, gz = 1.f - m.z;
        const float a00 = gx * gy, a01 = gx * m.y, a10 = m.x * gy, a11 = m.x * m.y;
        acc[0] = fmaf(a00 * gz,  v, acc[0]);
        acc[1] = fmaf(a00 * m.z, v, acc[1]);
        acc[2] = fmaf(a01 * gz,  v, acc[2]);
        acc[3] = fmaf(a01 * m.z, v, acc[3]);
        acc[4] = fmaf(a10 * gz,  v, acc[4]);
        acc[5] = fmaf(a10 * m.z, v, acc[5]);
        acc[6] = fmaf(a11 * gz,  v, acc[6]);
        acc[7] = fmaf(a11 * m.z, v, acc[7]);
    }

    __shared__ float red[16 * 8 * 32];        // 16 KB
    #pragma unroll
    for (int k = 0; k < 8; k++) red[sub*256 + k*32 + c] = acc[k];
    __syncthreads();
    if (t < 256) {
        const int k = t >> 5, cc = t & 31;
        float s = 0.f;
        #pragma unroll
        for (int ss = 0; ss < 16; ss++) s += red[ss*256 + k*32 + cc];
        Mbuf[(blockIdx.x*8 + k)*32 + cc] = s;   // [cell][split][k][c]
    }
}

// ---------------------------------------------------------------------------
// K2: flush: img[x,y,z][c] = sum_{k,split} M[(x-dx)&7,...][s][k][c]
// ---------------------------------------------------------------------------
__global__ __launch_bounds__(256) void k_flush(
    const float* __restrict__ Mbuf, float* __restrict__ img)
{
    const int tid = blockIdx.x*256 + threadIdx.x;   // 0..4095 (float4 units)
    if (tid >= 4096) return;
    const int cell = tid >> 3, c4 = tid & 7;
    const int x = cell >> 6, y = (cell >> 3) & 7, z = cell & 7;
    const float4* M4 = (const float4*)Mbuf;         // [512][SPLIT][8][8]
    float4 s = {0.f, 0.f, 0.f, 0.f};
    #pragma unroll
    for (int k = 0; k < 8; k++) {
        const int dx = (k >> 2) & 1, dy = (k >> 1) & 1, dz = k & 1;
        const int b = ((x - dx) & 7)*64 + ((y - dy) & 7)*8 + ((z - dz) & 7);
        #pragma unroll
        for (int sp = 0; sp < SPLIT; sp++) {
            const float4 v = M4[((b*SPLIT + sp)*8 + k)*8 + c4];
            s.x += v.x; s.y += v.y; s.z += v.z; s.w += v.w;
        }
    }
    ((float4*)img)[tid] = s;
}

// ---------------------------------------------------------------------------
// K3/K4/K5: periodic 3x3x3 conv, DHWOI weights [3][3][3][32][32].
// ACT=0: out = conv(in).  ACT=1: out = in + silu(conv(in)).
// Block = (ix,iy). Stage only the 3x3 column neighborhood (72 cells, 10KB,
// stride-36 pad). Threads 256 = (iz 8, coutg 8, wave 'part' 4).
// Each thread computes 4 couts (coutg + 8q) over its wave's tap subset:
// activations loaded once per tap, reused 4x (54 ds_read_b128/thread).
// Cross-wave partial reduce in LDS.
// ---------------------------------------------------------------------------
template<int ACT>
__global__ __launch_bounds__(256) void k_conv(
    const float* __restrict__ in_lat,
    const float* __restrict__ w,
    float* __restrict__ out_lat)
{
    __shared__ float lds[72*36];        // 10368 B
    __shared__ float red2[4*256];       // 4 KB
    const int t = threadIdx.x;
    const int ix = blockIdx.x >> 3, iy = blockIdx.x & 7;

    // stage 9-column periodic neighborhood: 72 cells x 8 float4 = 576
    for (int i = t; i < 576; i += 256) {
        const int cellL = i >> 3, c4 = i & 7;
        const int s9 = cellL >> 3, nz = cellL & 7;   // s9 = jx*3+jy
        const int jx = s9 / 3, jy = s9 - jx*3;
        const int gx = (ix + jx + 7) & 7, gy = (iy + jy + 7) & 7;
        const float4 v = ((const float4*)in_lat)[(gx*64 + gy*8 + nz)*8 + c4];
        *(float4*)&lds[cellL*36 + c4*4] = v;
    }
    __syncthreads();

    const int iz    = t & 7;
    const int coutg = (t >> 3) & 7;
    const int part  = t >> 6;            // wave id, 0..3: tap subset

    float4 acc4[4];
    #pragma unroll
    for (int q = 0; q < 4; q++) acc4[q] = make_float4(0.f,0.f,0.f,0.f);

    const int tau0 = (part * 27) >> 2, tau1 = ((part + 1) * 27) >> 2;
    for (int tau = tau0; tau < tau1; ++tau) {
        const int kd = tau / 9, r = tau - kd*9;
        const int kh = r / 3,  kw = r - kh*3;
        const int nz = (iz + kw + 7) & 7;
        const float* lrow = &lds[((kd*3 + kh)*8 + nz)*36];
        float4 av[8];
        #pragma unroll
        for (int c4i = 0; c4i < 8; c4i++) av[c4i] = *(const float4*)(lrow + c4i*4);
        #pragma unroll
        for (int q = 0; q < 4; q++) {
            const float* wrow = &w[(size_t)(tau*32 + coutg + 8*q)*32];
            #pragma unroll
            for (int c4i = 0; c4i < 8; c4i++) {
                const float4 b = *(const float4*)(wrow + c4i*4);
                acc4[q].x = fmaf(av[c4i].x, b.x, acc4[q].x);
                acc4[q].y = fmaf(av[c4i].y, b.y, acc4[q].y);
                acc4[q].z = fmaf(av[c4i].z, b.z, acc4[q].z);
                acc4[q].w = fmaf(av[c4i].w, b.w, acc4[q].w);
            }
        }
    }
    #pragma unroll
    for (int q = 0; q < 4; q++) {
        const int cout = coutg + 8*q;
        red2[part*256 + cout*8 + iz] =
            (acc4[q].x + acc4[q].y) + (acc4[q].z + acc4[q].w);
    }
    __syncthreads();

    // t = cout*8 + iz  (all 256 threads produce one output)
    const int ocout = t >> 3, oiz = t & 7;
    float s = red2[t] + red2[256 + t] + red2[512 + t] + red2[768 + t];
    const int oidx = (ix*64 + iy*8 + oiz)*32 + ocout;
    if (ACT == 1) {
        const float rres = in_lat[oidx];
        s = rres + s / (1.f + expf(-s));    // r + silu(conv)
    }
    out_lat[oidx] = s;
}

// ---------------------------------------------------------------------------
// K6: agg[cell] = sum over 8 corner-offset cells of out_lat
// ---------------------------------------------------------------------------
__global__ __launch_bounds__(256) void k_agg(
    const float* __restrict__ out_lat, float* __restrict__ agg)
{
    const int tid = blockIdx.x*256 + threadIdx.x;   // 0..4095
    if (tid >= 4096) return;
    const int cell = tid >> 3, c4 = tid & 7;
    const int ix = cell >> 6, iy = (cell >> 3) & 7, iz = cell & 7;
    float4 s = {0.f,0.f,0.f,0.f};
    #pragma unroll
    for (int k = 0; k < 8; k++) {
        const int nx = (ix + ((k>>2)&1)) & 7;
        const int ny = (iy + ((k>>1)&1)) & 7;
        const int nz = (iz + (k&1)) & 7;
        const float4 v = ((const float4*)out_lat)[(nx*64 + ny*8 + nz)*8 + c4];
        s.x += v.x; s.y += v.y; s.z += v.z; s.w += v.w;
    }
    ((float4*)agg)[tid] = s;
}

// ---------------------------------------------------------------------------
// K7: gather -- out[p] = agg[base_cell(p)]
// ---------------------------------------------------------------------------
__global__ __launch_bounds__(256) void k_gather(
    const float* __restrict__ pos,
    const float* __restrict__ agg,
    float* __restrict__ out,
    int n)
{
    const int tid = blockIdx.x*256 + threadIdx.x;   // over n*8
    const int p = tid >> 3, c4 = tid & 7;
    if (p >= n) return;
    const int ix = ((int)floorf(pos[3*p+0]*8.f)) & 7;
    const int iy = ((int)floorf(pos[3*p+1]*8.f)) & 7;
    const int iz = ((int)floorf(pos[3*p+2]*8.f)) & 7;
    ((float4*)out)[tid] = ((const float4*)agg)[(ix*64 + iy*8 + iz)*8 + c4];
}

// ---------------------------------------------------------------------------
extern "C" void kernel_launch(void* const* d_in, const int* in_sizes, int n_in,
                              void* d_out, int out_size, void* d_ws, size_t ws_size,
                              hipStream_t stream)
{
    const float* pos  = (const float*)d_in[0];   // [N,3]
    const float* feat = (const float*)d_in[1];   // [N,32]
    const float* wenc = (const float*)d_in[2];   // [3,3,3,32,32]
    const float* winn = (const float*)d_in[3];   // [1,3,3,3,32,32]
    const float* wdec = (const float*)d_in[4];   // [3,3,3,32,32]
    float* out = (float*)d_out;
    const int n = in_sizes[0] / 3;

    // ws layout (16B-aligned blocks first); total ~11.4 MB
    float4* meta     = (float4*)d_ws;                       // n float4 (8 MB)
    float*  Mbuf     = (float*)(meta + n);                  // 512*SPLIT*8*32 (2 MB)
    float*  img      = Mbuf + NCELL*SPLIT*8*32;
    float*  h1       = img  + IMG_F;
    float*  h2       = h1   + IMG_F;
    float*  olat     = h2   + IMG_F;
    float*  aggb     = olat + IMG_F;
    int*    blockCnt = (int*)(aggb + IMG_F);                // NCELL*NB
    int*    relBase  = blockCnt + NCELL*NB;                 // NCELL*NB
    int*    cellTot  = relBase + NCELL*NB;                  // 512
    int*    binStart = cellTot + NCELL;                     // 513

    k_hist   <<<NB,    256, 0, stream>>>(pos, n, blockCnt);
    k_colscan<<<NCELL, NB,  0, stream>>>(blockCnt, relBase, cellTot);
    k_scan512<<<1,   NCELL, 0, stream>>>(cellTot, binStart);
    k_reorder<<<NB,    256, 0, stream>>>(pos, n, relBase, binStart, meta);
    k_accum  <<<NCELL*SPLIT, 512, 0, stream>>>(meta, feat, binStart, Mbuf);
    k_flush  <<<16,    256, 0, stream>>>(Mbuf, img);
    k_conv<0><<<64,    256, 0, stream>>>(img, wenc, h1);
    k_conv<1><<<64,    256, 0, stream>>>(h1,  winn, h2);
    k_conv<0><<<64,    256, 0, stream>>>(h2,  wdec, olat);
    k_agg    <<<16,    256, 0, stream>>>(olat, aggb);
    const int gblocks = (n*8 + 255)/256;
    k_gather <<<gblocks, 256, 0, stream>>>(pos, aggb, out, n);
}

// Round 6
// 177.640 us; speedup vs baseline: 4.5273x; 1.1220x over previous
//
#include <hip/hip_runtime.h>
#include <hip/hip_bf16.h>
#include <math.h>

#define NCELL 512          // 8^3 cells
#define IMG_F 16384        // NCELL * 32 floats = 64 KB
#define NB    256          // sort blocks (hist/reorder share this grid)
#define SPLIT 4            // accum blocks per cell

// ---------------------------------------------------------------------------
// K0: per-block histogram -> blockCnt[cell][b]   (no global atomics)
// ---------------------------------------------------------------------------
__global__ __launch_bounds__(256) void k_hist(
    const float* __restrict__ pos, int n, int* __restrict__ blockCnt)
{
    __shared__ int h[NCELL];
    const int t = threadIdx.x;
    for (int i = t; i < NCELL; i += 256) h[i] = 0;
    __syncthreads();
    const int stride = NB * 256;
    for (int p = blockIdx.x * 256 + t; p < n; p += stride) {
        const int ix = ((int)floorf(pos[3*p+0]*8.f)) & 7;
        const int iy = ((int)floorf(pos[3*p+1]*8.f)) & 7;
        const int iz = ((int)floorf(pos[3*p+2]*8.f)) & 7;
        atomicAdd(&h[ix*64 + iy*8 + iz], 1);
    }
    __syncthreads();
    for (int i = t; i < NCELL; i += 256)
        blockCnt[i * NB + blockIdx.x] = h[i];
}

// ---------------------------------------------------------------------------
// K0b: per-cell scan over the NB blocks. block = cell, thread = sort-block.
// ---------------------------------------------------------------------------
__global__ __launch_bounds__(NB) void k_colscan(
    const int* __restrict__ blockCnt,
    int* __restrict__ relBase,
    int* __restrict__ cellTot)
{
    __shared__ int s[NB];
    const int cell = blockIdx.x, b = threadIdx.x;
    const int v = blockCnt[cell * NB + b];     // coalesced
    s[b] = v;
    __syncthreads();
    int acc = v;
    for (int off = 1; off < NB; off <<= 1) {
        const int add = (b >= off) ? s[b - off] : 0;
        __syncthreads();
        acc += add;
        s[b] = acc;
        __syncthreads();
    }
    relBase[cell * NB + b] = acc - v;
    if (b == NB - 1) cellTot[cell] = acc;
}

// ---------------------------------------------------------------------------
// K0c: exclusive scan of 512 cell totals -> binStart[513]
// ---------------------------------------------------------------------------
__global__ __launch_bounds__(NCELL) void k_scan512(
    const int* __restrict__ cellTot, int* __restrict__ binStart)
{
    __shared__ int s[NCELL];
    const int t = threadIdx.x;
    const int v = cellTot[t];
    s[t] = v;
    __syncthreads();
    int acc = v;
    for (int off = 1; off < NCELL; off <<= 1) {
        const int add = (t >= off) ? s[t - off] : 0;
        __syncthreads();
        acc += add;
        s[t] = acc;
        __syncthreads();
    }
    binStart[t] = acc - v;
    if (t == NCELL - 1) binStart[NCELL] = acc;
}

// ---------------------------------------------------------------------------
// K0d: reorder -- same point partition as k_hist; slots from LDS cursors
// seeded with binStart[cell] + relBase[cell][b]. Zero global atomics.
// ---------------------------------------------------------------------------
__global__ __launch_bounds__(256) void k_reorder(
    const float* __restrict__ pos, int n,
    const int* __restrict__ relBase, const int* __restrict__ binStart,
    float4* __restrict__ meta)
{
    __shared__ int cur[NCELL];
    const int t = threadIdx.x;
    for (int i = t; i < NCELL; i += 256)
        cur[i] = binStart[i] + relBase[i * NB + blockIdx.x];
    __syncthreads();
    const int stride = NB * 256;
    for (int p = blockIdx.x * 256 + t; p < n; p += stride) {
        const float sx = pos[3*p+0]*8.f, sy = pos[3*p+1]*8.f, sz = pos[3*p+2]*8.f;
        const float bx = floorf(sx), by = floorf(sy), bz = floorf(sz);
        const int ix = ((int)bx) & 7, iy = ((int)by) & 7, iz = ((int)bz) & 7;
        const int cell = ix*64 + iy*8 + iz;
        const int slot = atomicAdd(&cur[cell], 1);     // LDS ds_add_rtn
        meta[slot] = make_float4(sx - bx, sy - by, sz - bz, __int_as_float(p));
    }
}

// ---------------------------------------------------------------------------
// K1: per-(cell,split) register accumulation of M[8][32].
// grid = NCELL*SPLIT, 512 thr: c = t&31, sub = t>>5 (16 point subsets).
// Batch-4 load pipeline: 4 meta loads -> 4 feat loads -> 32 FMAs, so ~8
// VMEM in flight per thread. __launch_bounds__(512,8) pins VGPR<=64 ->
// 32 waves/CU.
// ---------------------------------------------------------------------------
__global__ __launch_bounds__(512, 8) void k_accum(
    const float4* __restrict__ meta,
    const float* __restrict__ feat,
    const int* __restrict__ binStart,
    float* __restrict__ Mbuf)
{
    const int cell  = blockIdx.x >> 2;
    const int split = blockIdx.x & (SPLIT - 1);
    const int t = threadIdx.x;
    const int c = t & 31, sub = t >> 5;       // sub in 0..15
    const int b0 = binStart[cell], cnt = binStart[cell + 1] - b0;
    const int s0 = b0 + (cnt * split) / SPLIT;
    const int s1 = b0 + (cnt * (split + 1)) / SPLIT;

    float acc[8];
    #pragma unroll
    for (int k = 0; k < 8; k++) acc[k] = 0.f;

    int i = s0 + sub;
    // steady state: 4 points per iteration (stride 16 per sub-slot)
    for (; i + 48 < s1; i += 64) {
        float4 m[4];
        float  v[4];
        #pragma unroll
        for (int j = 0; j < 4; j++) m[j] = meta[i + 16*j];
        #pragma unroll
        for (int j = 0; j < 4; j++)
            v[j] = feat[(size_t)__float_as_int(m[j].w) * 32 + c];
        #pragma unroll
        for (int j = 0; j < 4; j++) {
            const float gx = 1.f - m[j].x, gy = 1.f - m[j].y, gz = 1.f - m[j].z;
            const float a00 = gx*gy, a01 = gx*m[j].y, a10 = m[j].x*gy, a11 = m[j].x*m[j].y;
            acc[0] = fmaf(a00 * gz,     v[j], acc[0]);
            acc[1] = fmaf(a00 * m[j].z, v[j], acc[1]);
            acc[2] = fmaf(a01 * gz,     v[j], acc[2]);
            acc[3] = fmaf(a01 * m[j].z, v[j], acc[3]);
            acc[4] = fmaf(a10 * gz,     v[j], acc[4]);
            acc[5] = fmaf(a10 * m[j].z, v[j], acc[5]);
            acc[6] = fmaf(a11 * gz,     v[j], acc[6]);
            acc[7] = fmaf(a11 * m[j].z, v[j], acc[7]);
        }
    }
    // tail
    for (; i < s1; i += 16) {
        const float4 m = meta[i];
        const float v = feat[(size_t)__float_as_int(m.w) * 32 + c];
        const float gx = 1.f - m.x, gy = 1.f - m.y, gz = 1.f - m.z;
        const float a00 = gx*gy, a01 = gx*m.y, a10 = m.x*gy, a11 = m.x*m.y;
        acc[0] = fmaf(a00 * gz,  v, acc[0]);
        acc[1] = fmaf(a00 * m.z, v, acc[1]);
        acc[2] = fmaf(a01 * gz,  v, acc[2]);
        acc[3] = fmaf(a01 * m.z, v, acc[3]);
        acc[4] = fmaf(a10 * gz,  v, acc[4]);
        acc[5] = fmaf(a10 * m.z, v, acc[5]);
        acc[6] = fmaf(a11 * gz,  v, acc[6]);
        acc[7] = fmaf(a11 * m.z, v, acc[7]);
    }

    __shared__ float red[16 * 8 * 32];        // 16 KB
    #pragma unroll
    for (int k = 0; k < 8; k++) red[sub*256 + k*32 + c] = acc[k];
    __syncthreads();
    if (t < 256) {
        const int k = t >> 5, cc = t & 31;
        float s = 0.f;
        #pragma unroll
        for (int ss = 0; ss < 16; ss++) s += red[ss*256 + k*32 + cc];
        Mbuf[(blockIdx.x*8 + k)*32 + cc] = s;   // [cell][split][k][c]
    }
}

// ---------------------------------------------------------------------------
// K2: flush: img[x,y,z][c] = sum_{k,split} M[(x-dx)&7,...][s][k][c]
// ---------------------------------------------------------------------------
__global__ __launch_bounds__(256) void k_flush(
    const float* __restrict__ Mbuf, float* __restrict__ img)
{
    const int tid = blockIdx.x*256 + threadIdx.x;   // 0..4095 (float4 units)
    if (tid >= 4096) return;
    const int cell = tid >> 3, c4 = tid & 7;
    const int x = cell >> 6, y = (cell >> 3) & 7, z = cell & 7;
    const float4* M4 = (const float4*)Mbuf;         // [512][SPLIT][8][8]
    float4 s = {0.f, 0.f, 0.f, 0.f};
    #pragma unroll
    for (int k = 0; k < 8; k++) {
        const int dx = (k >> 2) & 1, dy = (k >> 1) & 1, dz = k & 1;
        const int b = ((x - dx) & 7)*64 + ((y - dy) & 7)*8 + ((z - dz) & 7);
        #pragma unroll
        for (int sp = 0; sp < SPLIT; sp++) {
            const float4 v = M4[((b*SPLIT + sp)*8 + k)*8 + c4];
            s.x += v.x; s.y += v.y; s.z += v.z; s.w += v.w;
        }
    }
    ((float4*)img)[tid] = s;
}

// ---------------------------------------------------------------------------
// K3/K4/K5: periodic 3x3x3 conv, DHWOI weights [3][3][3][32][32].
// ACT=0: out = conv(in).  ACT=1: out = in + silu(conv(in)).
// Grid = 256 blocks: block = (ix,iy) x cout-octet.  512 thr =
// (iz 8) x (co8 8) x (tap-part 8).  Stage the 3x3 column neighborhood
// (72 cells, 10KB, stride-36 pad).  Each thread: 1 cout over ~3-4 taps.
// Cross-part reduce in LDS.
// ---------------------------------------------------------------------------
template<int ACT>
__global__ __launch_bounds__(512) void k_conv(
    const float* __restrict__ in_lat,
    const float* __restrict__ w,
    float* __restrict__ out_lat)
{
    __shared__ float lds[72*36];        // 10368 B
    __shared__ float red2[8*64];        // 2 KB
    const int t = threadIdx.x;
    const int ixy = blockIdx.x >> 2;
    const int qq  = blockIdx.x & 3;     // cout octet
    const int ix = ixy >> 3, iy = ixy & 7;

    // stage 9-column periodic neighborhood: 72 cells x 8 float4 = 576
    for (int i = t; i < 576; i += 512) {
        const int cellL = i >> 3, c4 = i & 7;
        const int s9 = cellL >> 3, nz = cellL & 7;   // s9 = jx*3+jy
        const int jx = s9 / 3, jy = s9 - jx*3;
        const int gx = (ix + jx + 7) & 7, gy = (iy + jy + 7) & 7;
        const float4 v = ((const float4*)in_lat)[(gx*64 + gy*8 + nz)*8 + c4];
        *(float4*)&lds[cellL*36 + c4*4] = v;
    }
    __syncthreads();

    const int iz   = t & 7;
    const int co8  = (t >> 3) & 7;
    const int part = t >> 6;            // 0..7 tap subset
    const int cout = qq*8 + co8;

    float4 acc = {0.f,0.f,0.f,0.f};
    const int tau0 = (part * 27) >> 3, tau1 = ((part + 1) * 27) >> 3;
    for (int tau = tau0; tau < tau1; ++tau) {
        const int kd = tau / 9, r = tau - kd*9;
        const int kh = r / 3,  kw = r - kh*3;
        const int nz = (iz + kw + 7) & 7;
        const float* lrow = &lds[((kd*3 + kh)*8 + nz)*36];
        const float* wrow = &w[(size_t)(tau*32 + cout)*32];
        #pragma unroll
        for (int c4i = 0; c4i < 8; c4i++) {
            const float4 a = *(const float4*)(lrow + c4i*4);
            const float4 b = *(const float4*)(wrow + c4i*4);
            acc.x = fmaf(a.x, b.x, acc.x);
            acc.y = fmaf(a.y, b.y, acc.y);
            acc.z = fmaf(a.z, b.z, acc.z);
            acc.w = fmaf(a.w, b.w, acc.w);
        }
    }
    red2[part*64 + co8*8 + iz] = (acc.x + acc.y) + (acc.z + acc.w);
    __syncthreads();

    if (t < 64) {
        const int oco8 = t >> 3, oiz = t & 7;
        float s = 0.f;
        #pragma unroll
        for (int pp = 0; pp < 8; pp++) s += red2[pp*64 + t];
        const int oidx = (ix*64 + iy*8 + oiz)*32 + qq*8 + oco8;
        if (ACT == 1) {
            const float rres = in_lat[oidx];
            s = rres + s / (1.f + expf(-s));    // r + silu(conv)
        }
        out_lat[oidx] = s;
    }
}

// ---------------------------------------------------------------------------
// K6: agg[cell] = sum over 8 corner-offset cells of out_lat
// ---------------------------------------------------------------------------
__global__ __launch_bounds__(256) void k_agg(
    const float* __restrict__ out_lat, float* __restrict__ agg)
{
    const int tid = blockIdx.x*256 + threadIdx.x;   // 0..4095
    if (tid >= 4096) return;
    const int cell = tid >> 3, c4 = tid & 7;
    const int ix = cell >> 6, iy = (cell >> 3) & 7, iz = cell & 7;
    float4 s = {0.f,0.f,0.f,0.f};
    #pragma unroll
    for (int k = 0; k < 8; k++) {
        const int nx = (ix + ((k>>2)&1)) & 7;
        const int ny = (iy + ((k>>1)&1)) & 7;
        const int nz = (iz + (k&1)) & 7;
        const float4 v = ((const float4*)out_lat)[(nx*64 + ny*8 + nz)*8 + c4];
        s.x += v.x; s.y += v.y; s.z += v.z; s.w += v.w;
    }
    ((float4*)agg)[tid] = s;
}

// ---------------------------------------------------------------------------
// K7: gather -- out[p] = agg[base_cell(p)]
// ---------------------------------------------------------------------------
__global__ __launch_bounds__(256) void k_gather(
    const float* __restrict__ pos,
    const float* __restrict__ agg,
    float* __restrict__ out,
    int n)
{
    const int tid = blockIdx.x*256 + threadIdx.x;   // over n*8
    const int p = tid >> 3, c4 = tid & 7;
    if (p >= n) return;
    const int ix = ((int)floorf(pos[3*p+0]*8.f)) & 7;
    const int iy = ((int)floorf(pos[3*p+1]*8.f)) & 7;
    const int iz = ((int)floorf(pos[3*p+2]*8.f)) & 7;
    ((float4*)out)[tid] = ((const float4*)agg)[(ix*64 + iy*8 + iz)*8 + c4];
}

// ---------------------------------------------------------------------------
extern "C" void kernel_launch(void* const* d_in, const int* in_sizes, int n_in,
                              void* d_out, int out_size, void* d_ws, size_t ws_size,
                              hipStream_t stream)
{
    const float* pos  = (const float*)d_in[0];   // [N,3]
    const float* feat = (const float*)d_in[1];   // [N,32]
    const float* wenc = (const float*)d_in[2];   // [3,3,3,32,32]
    const float* winn = (const float*)d_in[3];   // [1,3,3,3,32,32]
    const float* wdec = (const float*)d_in[4];   // [3,3,3,32,32]
    float* out = (float*)d_out;
    const int n = in_sizes[0] / 3;

    // ws layout (16B-aligned blocks first); total ~11.4 MB
    float4* meta     = (float4*)d_ws;                       // n float4 (8 MB)
    float*  Mbuf     = (float*)(meta + n);                  // 512*SPLIT*8*32 (2 MB)
    float*  img      = Mbuf + NCELL*SPLIT*8*32;
    float*  h1       = img  + IMG_F;
    float*  h2       = h1   + IMG_F;
    float*  olat     = h2   + IMG_F;
    float*  aggb     = olat + IMG_F;
    int*    blockCnt = (int*)(aggb + IMG_F);                // NCELL*NB
    int*    relBase  = blockCnt + NCELL*NB;                 // NCELL*NB
    int*    cellTot  = relBase + NCELL*NB;                  // 512
    int*    binStart = cellTot + NCELL;                     // 513

    k_hist   <<<NB,    256, 0, stream>>>(pos, n, blockCnt);
    k_colscan<<<NCELL, NB,  0, stream>>>(blockCnt, relBase, cellTot);
    k_scan512<<<1,   NCELL, 0, stream>>>(cellTot, binStart);
    k_reorder<<<NB,    256, 0, stream>>>(pos, n, relBase, binStart, meta);
    k_accum  <<<NCELL*SPLIT, 512, 0, stream>>>(meta, feat, binStart, Mbuf);
    k_flush  <<<16,    256, 0, stream>>>(Mbuf, img);
    k_conv<0><<<256,   512, 0, stream>>>(img, wenc, h1);
    k_conv<1><<<256,   512, 0, stream>>>(h1,  winn, h2);
    k_conv<0><<<256,   512, 0, stream>>>(h2,  wdec, olat);
    k_agg    <<<16,    256, 0, stream>>>(olat, aggb);
    const int gblocks = (n*8 + 255)/256;
    k_gather <<<gblocks, 256, 0, stream>>>(pos, aggb, out, n);
}